// Round 1
// baseline (1367.890 us; speedup 1.0000x reference)
//
#include <hip/hip_runtime.h>
#include <cstdint>

#define N_GRAPHS 20000

// ---------------- degree ----------------
__global__ void count_in_deg(const int* __restrict__ dst, int* __restrict__ cnt, int E) {
  int i = blockIdx.x * blockDim.x + threadIdx.x;
  int stride = gridDim.x * blockDim.x;
  for (int e = i; e < E; e += stride) atomicAdd(&cnt[dst[e]], 1);
}

__global__ void inv_sqrt_deg(const int* __restrict__ cnt, float* __restrict__ isq, int N) {
  int i = blockIdx.x * blockDim.x + threadIdx.x;
  if (i < N) isq[i] = rsqrtf((float)(cnt[i] + 1));
}

// ---------------- node GEMM: out[N,64] = in[N,64] @ W[64,64] ----------------
__global__ __launch_bounds__(256) void gemm_n64(const float* __restrict__ in,
                                                const float* __restrict__ W,
                                                float* __restrict__ out, int N) {
  __shared__ float Wl[64 * 64];
  __shared__ float Rl[64 * 65];  // +1 pad breaks bank aliasing on Rl[r][k] reads
  int tid = threadIdx.x;
#pragma unroll
  for (int v = 0; v < 4; ++v) {
    int u = tid + v * 256;  // float4 units, 0..1023
    *(float4*)&Wl[u * 4] = *(const float4*)&W[u * 4];
  }
  long base_row = (long)blockIdx.x * 64;
#pragma unroll
  for (int v = 0; v < 4; ++v) {
    int u = tid + v * 256;
    int r = u >> 4;
    int k = (u & 15) * 4;
    long row = base_row + r;
    float4 val = make_float4(0.f, 0.f, 0.f, 0.f);
    if (row < N) val = *(const float4*)&in[row * 64 + k];
    *(float4*)&Rl[r * 65 + k] = val;
  }
  __syncthreads();
  int r = tid >> 2;
  int c0 = (tid & 3) * 16;
  float acc[16];
#pragma unroll
  for (int j = 0; j < 16; ++j) acc[j] = 0.f;
#pragma unroll 4
  for (int k = 0; k < 64; ++k) {
    float a = Rl[r * 65 + k];
#pragma unroll
    for (int j = 0; j < 16; ++j) acc[j] += a * Wl[k * 64 + c0 + j];
  }
  long row = base_row + r;
  if (row < N) {
#pragma unroll
    for (int v = 0; v < 4; ++v) {
      *(float4*)&out[row * 64 + c0 + v * 4] =
          make_float4(acc[v * 4], acc[v * 4 + 1], acc[v * 4 + 2], acc[v * 4 + 3]);
    }
  }
}

// ---------------- edge scatter: agg[dst] += h[src] * isq[src]*isq[dst] ----------------
__global__ void edge_scatter(const float* __restrict__ h, const int* __restrict__ src,
                             const int* __restrict__ dst, const float* __restrict__ isq,
                             float* __restrict__ agg, int E) {
  int lane = threadIdx.x & 63;
  int wid = (blockIdx.x * blockDim.x + threadIdx.x) >> 6;
  int nw = (gridDim.x * blockDim.x) >> 6;
  for (int e = wid; e < E; e += nw) {
    int s = src[e];
    int d = dst[e];
    float w = isq[s] * isq[d];
    float v = h[(long)s * 64 + lane] * w;
    atomicAdd(&agg[(long)d * 64 + lane], v);
  }
}

// ---------------- combine: e = relu(agg + h*(1/deg) + b) in place ----------------
__global__ void combine_relu(float* __restrict__ agg, const float* __restrict__ h,
                             const float* __restrict__ isq, const float* __restrict__ b, int N) {
  int i = blockIdx.x * blockDim.x + threadIdx.x;
  if (i >= N * 16) return;
  int node = i >> 4;
  int c4 = (i & 15) * 4;
  float is = isq[node];
  float idg = is * is;
  float4 a = *(float4*)&agg[(long)node * 64 + c4];
  float4 hh = *(const float4*)&h[(long)node * 64 + c4];
  float4 bb = *(const float4*)&b[c4];
  float4 r;
  r.x = fmaxf(fmaf(hh.x, idg, a.x) + bb.x, 0.f);
  r.y = fmaxf(fmaf(hh.y, idg, a.y) + bb.y, 0.f);
  r.z = fmaxf(fmaf(hh.z, idg, a.z) + bb.z, 0.f);
  r.w = fmaxf(fmaf(hh.w, idg, a.w) + bb.w, 0.f);
  *(float4*)&agg[(long)node * 64 + c4] = r;
}

// ---------------- graph segment offsets from sorted batch_idx ----------------
__global__ void seg_offsets(const int* __restrict__ batch, int* __restrict__ off, int N, int G) {
  int i = blockIdx.x * blockDim.x + threadIdx.x;
  if (i >= N) return;
  int b = batch[i];
  if (i == 0) {
    for (int g = 0; g <= b; ++g) off[g] = 0;
  } else {
    int pb = batch[i - 1];
    for (int g = pb + 1; g <= b; ++g) off[g] = i;
  }
  if (i == N - 1) {
    for (int g = b + 1; g <= G; ++g) off[g] = N;
  }
}

// ---------------- mean pool: wave per graph ----------------
__global__ void pool_mean(const float* __restrict__ e2, const int* __restrict__ off,
                          float* __restrict__ ge, int G) {
  int lane = threadIdx.x & 63;
  int wid = (blockIdx.x * blockDim.x + threadIdx.x) >> 6;
  int nw = (gridDim.x * blockDim.x) >> 6;
  for (int g = wid; g < G; g += nw) {
    int s = off[g];
    int e = off[g + 1];
    float sum = 0.f;
    for (int n = s; n < e; ++n) sum += e2[(long)n * 64 + lane];
    ge[(long)g * 64 + lane] = sum / fmaxf((float)(e - s), 1.f);
  }
}

// ---------------- pair MLP ----------------
#define PPB 16
__global__ __launch_bounds__(256) void pair_mlp(const float* __restrict__ ge,
                                                const int* __restrict__ dp,  // [2][P]
                                                const float* __restrict__ Wr1,
                                                const float* __restrict__ br1,
                                                const float* __restrict__ Wr2,
                                                const float* __restrict__ br2,
                                                float* __restrict__ out, int P) {
  __shared__ float feat[PPB][128];
  __shared__ int pidx[2][PPB];
  __shared__ float red[4][PPB];
  int tid = threadIdx.x;
  int base = blockIdx.x * PPB;
  if (tid < PPB) {
    int p = base + tid;
    pidx[0][tid] = (p < P) ? dp[p] : 0;
    pidx[1][tid] = (p < P) ? dp[P + p] : 0;
  }
  __syncthreads();
#pragma unroll
  for (int i = 0; i < 8; ++i) {
    int f = tid + i * 256;  // 0..2047
    int p = f >> 7;
    int k = f & 127;
    int g = (k < 64) ? pidx[0][p] : pidx[1][p];
    feat[p][k] = ge[(long)g * 64 + (k & 63)];
  }
  __syncthreads();
  int j = tid;  // hidden unit 0..255
  float w2 = Wr2[j];
  float b1v = br1[j];
  float acc[PPB];
#pragma unroll
  for (int p = 0; p < PPB; ++p) acc[p] = 0.f;
  for (int k4 = 0; k4 < 128; k4 += 4) {
    float w0 = Wr1[(k4 + 0) * 256 + j];
    float w1 = Wr1[(k4 + 1) * 256 + j];
    float wv2 = Wr1[(k4 + 2) * 256 + j];
    float w3 = Wr1[(k4 + 3) * 256 + j];
#pragma unroll
    for (int p = 0; p < PPB; ++p) {
      float4 f = *(const float4*)&feat[p][k4];
      acc[p] = fmaf(f.x, w0, acc[p]);
      acc[p] = fmaf(f.y, w1, acc[p]);
      acc[p] = fmaf(f.z, wv2, acc[p]);
      acc[p] = fmaf(f.w, w3, acc[p]);
    }
  }
  int wv = tid >> 6;
#pragma unroll
  for (int p = 0; p < PPB; ++p) {
    float hid = fmaxf(acc[p] + b1v, 0.f);
    float v = hid * w2;
    for (int o = 32; o > 0; o >>= 1) v += __shfl_down(v, o, 64);
    if ((tid & 63) == 0) red[wv][p] = v;
  }
  __syncthreads();
  if (tid < PPB) {
    int p = base + tid;
    if (p < P) out[p] = red[0][tid] + red[1][tid] + red[2][tid] + red[3][tid] + br2[0];
  }
}

extern "C" void kernel_launch(void* const* d_in, const int* in_sizes, int n_in,
                              void* d_out, int out_size, void* d_ws, size_t ws_size,
                              hipStream_t stream) {
  const float* x = (const float*)d_in[0];
  const int* ei = (const int*)d_in[1];
  const int* batch = (const int*)d_in[2];
  const int* dp = (const int*)d_in[3];
  const float* W1 = (const float*)d_in[4];
  const float* b1 = (const float*)d_in[5];
  const float* W2 = (const float*)d_in[6];
  const float* b2 = (const float*)d_in[7];
  const float* Wr1 = (const float*)d_in[8];
  const float* br1 = (const float*)d_in[9];
  const float* Wr2 = (const float*)d_in[10];
  const float* br2 = (const float*)d_in[11];
  float* out = (float*)d_out;

  int N = in_sizes[0] / 64;
  int E = in_sizes[1] / 2;
  int P = in_sizes[3] / 2;
  int G = N_GRAPHS;
  const int* src = ei;
  const int* dstp = ei + E;

  char* ws = (char*)d_ws;
  size_t o = 0;
  auto alloc = [&](size_t bytes) {
    void* p = ws + o;
    o += (bytes + 255) & ~(size_t)255;
    return p;
  };
  float* isq = (float*)alloc((size_t)N * 4);
  int* cnt = (int*)alloc((size_t)N * 4);
  int* goff = (int*)alloc((size_t)(G + 1) * 4);
  float* hbuf = (float*)alloc((size_t)N * 64 * 4);
  float* abuf = (float*)alloc((size_t)N * 64 * 4);
  float* ge = (float*)alloc((size_t)G * 64 * 4);

  hipMemsetAsync(cnt, 0, (size_t)N * 4, stream);
  count_in_deg<<<2048, 256, 0, stream>>>(dstp, cnt, E);
  inv_sqrt_deg<<<(N + 255) / 256, 256, 0, stream>>>(cnt, isq, N);

  int tiles = (N + 63) / 64;
  // conv1
  gemm_n64<<<tiles, 256, 0, stream>>>(x, W1, hbuf, N);
  hipMemsetAsync(abuf, 0, (size_t)N * 64 * 4, stream);
  edge_scatter<<<2048, 256, 0, stream>>>(hbuf, src, dstp, isq, abuf, E);
  combine_relu<<<(N * 16 + 255) / 256, 256, 0, stream>>>(abuf, hbuf, isq, b1, N);
  // conv2
  gemm_n64<<<tiles, 256, 0, stream>>>(abuf, W2, hbuf, N);
  hipMemsetAsync(abuf, 0, (size_t)N * 64 * 4, stream);
  edge_scatter<<<2048, 256, 0, stream>>>(hbuf, src, dstp, isq, abuf, E);
  combine_relu<<<(N * 16 + 255) / 256, 256, 0, stream>>>(abuf, hbuf, isq, b2, N);
  // pool
  seg_offsets<<<(N + 255) / 256, 256, 0, stream>>>(batch, goff, N, G);
  pool_mean<<<2048, 256, 0, stream>>>(abuf, goff, ge, G);
  // pair MLP
  pair_mlp<<<(P + PPB - 1) / PPB, 256, 0, stream>>>(ge, dp, Wr1, br1, Wr2, br2, out, P);
}

// Round 2
// 959.710 us; speedup vs baseline: 1.4253x; 1.4253x over previous
//
#include <hip/hip_runtime.h>
#include <cstdint>

#define N_GRAPHS 20000
#define SCAN_CHUNK 2048

// ---------------- degree ----------------
__global__ void count_in_deg(const int* __restrict__ dst, int* __restrict__ cnt, int E) {
  int i = blockIdx.x * blockDim.x + threadIdx.x;
  int stride = gridDim.x * blockDim.x;
  for (int e = i; e < E; e += stride) atomicAdd(&cnt[dst[e]], 1);
}

__global__ void inv_sqrt_deg(const int* __restrict__ cnt, float* __restrict__ isq, int N) {
  int i = blockIdx.x * blockDim.x + threadIdx.x;
  if (i < N) isq[i] = rsqrtf((float)(cnt[i] + 1));
}

// ---------------- prefix scan (exclusive) of cnt[N] -> rs[N+1] ----------------
__global__ __launch_bounds__(256) void scan1(const int* __restrict__ cnt, int* __restrict__ rs,
                                             int* __restrict__ bsum, int N) {
  __shared__ int lds[256];
  int t = threadIdx.x;
  int base = blockIdx.x * SCAN_CHUNK + t * 8;
  int v[8];
  int s = 0;
#pragma unroll
  for (int i = 0; i < 8; ++i) {
    v[i] = (base + i < N) ? cnt[base + i] : 0;
    s += v[i];
  }
  lds[t] = s;
  __syncthreads();
  for (int off = 1; off < 256; off <<= 1) {
    int x = (t >= off) ? lds[t - off] : 0;
    __syncthreads();
    lds[t] += x;
    __syncthreads();
  }
  if (t == 255) bsum[blockIdx.x] = lds[255];
  int run = (t > 0) ? lds[t - 1] : 0;
#pragma unroll
  for (int i = 0; i < 8; ++i) {
    if (base + i <= N) rs[base + i] = run;
    run += v[i];
  }
}

__global__ __launch_bounds__(256) void scan2(int* __restrict__ bsum, int nb) {
  __shared__ int lds[256];
  int t = threadIdx.x;
  lds[t] = (t < nb) ? bsum[t] : 0;
  __syncthreads();
  for (int off = 1; off < 256; off <<= 1) {
    int x = (t >= off) ? lds[t - off] : 0;
    __syncthreads();
    lds[t] += x;
    __syncthreads();
  }
  if (t < nb) bsum[t] = (t > 0) ? lds[t - 1] : 0;  // exclusive
}

__global__ void scan3(int* __restrict__ rs, const int* __restrict__ bsum, int Np1) {
  int i = blockIdx.x * blockDim.x + threadIdx.x;
  if (i < Np1) rs[i] += bsum[i / SCAN_CHUNK];
}

// ---------------- CSR fill ----------------
__global__ void csr_fill(const int* __restrict__ src, const int* __restrict__ dst,
                         const int* __restrict__ rs, int* __restrict__ fill,
                         int* __restrict__ csr, int E) {
  int i = blockIdx.x * blockDim.x + threadIdx.x;
  int stride = gridDim.x * blockDim.x;
  for (int e = i; e < E; e += stride) {
    int d = dst[e];
    int pos = rs[d] + atomicAdd(&fill[d], 1);
    csr[pos] = src[e];
  }
}

// ---------------- node GEMM: out[N,64] = in[N,64] @ W[64,64] ----------------
__global__ __launch_bounds__(256) void gemm_n64(const float* __restrict__ in,
                                                const float* __restrict__ W,
                                                float* __restrict__ out, int N) {
  __shared__ float Wl[64 * 64];
  __shared__ float Rl[64 * 65];
  int tid = threadIdx.x;
#pragma unroll
  for (int v = 0; v < 4; ++v) {
    int u = tid + v * 256;
    *(float4*)&Wl[u * 4] = *(const float4*)&W[u * 4];
  }
  long base_row = (long)blockIdx.x * 64;
#pragma unroll
  for (int v = 0; v < 4; ++v) {
    int u = tid + v * 256;
    int r = u >> 4;
    int k = (u & 15) * 4;
    long row = base_row + r;
    float4 val = make_float4(0.f, 0.f, 0.f, 0.f);
    if (row < N) val = *(const float4*)&in[row * 64 + k];
    *(float4*)&Rl[r * 65 + k] = val;
  }
  __syncthreads();
  int r = tid >> 2;
  int c0 = (tid & 3) * 16;
  float acc[16];
#pragma unroll
  for (int j = 0; j < 16; ++j) acc[j] = 0.f;
#pragma unroll 4
  for (int k = 0; k < 64; ++k) {
    float a = Rl[r * 65 + k];
#pragma unroll
    for (int j = 0; j < 16; ++j) acc[j] += a * Wl[k * 64 + c0 + j];
  }
  long row = base_row + r;
  if (row < N) {
#pragma unroll
    for (int v = 0; v < 4; ++v) {
      *(float4*)&out[row * 64 + c0 + v * 4] =
          make_float4(acc[v * 4], acc[v * 4 + 1], acc[v * 4 + 2], acc[v * 4 + 3]);
    }
  }
}

// ---------------- fused gather conv: out = relu(isq[d]*sum(h[s]*isq[s]) + h[d]/deg + b) --------
__global__ __launch_bounds__(256) void gather_conv(const float* __restrict__ h,
                                                   const int* __restrict__ csr,
                                                   const int* __restrict__ rs,
                                                   const float* __restrict__ isq,
                                                   const float* __restrict__ bias,
                                                   float* __restrict__ out, int N) {
  int lane = threadIdx.x & 63;
  int wid = (blockIdx.x * blockDim.x + threadIdx.x) >> 6;
  int nw = (gridDim.x * blockDim.x) >> 6;
  float bv = bias[lane];
  for (int d = wid; d < N; d += nw) {
    int j0 = rs[d];
    int j1 = rs[d + 1];
    float id = isq[d];
    float acc = 0.f;
    for (int j = j0; j < j1; ++j) {
      int s = csr[j];
      acc += h[(long)s * 64 + lane] * isq[s];
    }
    float hv = h[(long)d * 64 + lane];
    float r = fmaf(acc, id, hv * id * id) + bv;
    out[(long)d * 64 + lane] = fmaxf(r, 0.f);
  }
}

// ---------------- graph segment offsets from sorted batch_idx ----------------
__global__ void seg_offsets(const int* __restrict__ batch, int* __restrict__ off, int N, int G) {
  int i = blockIdx.x * blockDim.x + threadIdx.x;
  if (i >= N) return;
  int b = batch[i];
  if (i == 0) {
    for (int g = 0; g <= b; ++g) off[g] = 0;
  } else {
    int pb = batch[i - 1];
    for (int g = pb + 1; g <= b; ++g) off[g] = i;
  }
  if (i == N - 1) {
    for (int g = b + 1; g <= G; ++g) off[g] = N;
  }
}

// ---------------- mean pool: wave per graph ----------------
__global__ void pool_mean(const float* __restrict__ e2, const int* __restrict__ off,
                          float* __restrict__ ge, int G) {
  int lane = threadIdx.x & 63;
  int wid = (blockIdx.x * blockDim.x + threadIdx.x) >> 6;
  int nw = (gridDim.x * blockDim.x) >> 6;
  for (int g = wid; g < G; g += nw) {
    int s = off[g];
    int e = off[g + 1];
    float sum = 0.f;
    for (int n = s; n < e; ++n) sum += e2[(long)n * 64 + lane];
    ge[(long)g * 64 + lane] = sum / fmaxf((float)(e - s), 1.f);
  }
}

// ---------------- pair MLP ----------------
#define PPB 16
__global__ __launch_bounds__(256) void pair_mlp(const float* __restrict__ ge,
                                                const int* __restrict__ dp,
                                                const float* __restrict__ Wr1,
                                                const float* __restrict__ br1,
                                                const float* __restrict__ Wr2,
                                                const float* __restrict__ br2,
                                                float* __restrict__ out, int P) {
  __shared__ float feat[PPB][128];
  __shared__ int pidx[2][PPB];
  __shared__ float red[4][PPB];
  int tid = threadIdx.x;
  int base = blockIdx.x * PPB;
  if (tid < PPB) {
    int p = base + tid;
    pidx[0][tid] = (p < P) ? dp[p] : 0;
    pidx[1][tid] = (p < P) ? dp[P + p] : 0;
  }
  __syncthreads();
#pragma unroll
  for (int i = 0; i < 8; ++i) {
    int f = tid + i * 256;
    int p = f >> 7;
    int k = f & 127;
    int g = (k < 64) ? pidx[0][p] : pidx[1][p];
    feat[p][k] = ge[(long)g * 64 + (k & 63)];
  }
  __syncthreads();
  int j = tid;
  float w2 = Wr2[j];
  float b1v = br1[j];
  float acc[PPB];
#pragma unroll
  for (int p = 0; p < PPB; ++p) acc[p] = 0.f;
  for (int k4 = 0; k4 < 128; k4 += 4) {
    float w0 = Wr1[(k4 + 0) * 256 + j];
    float w1 = Wr1[(k4 + 1) * 256 + j];
    float wv2 = Wr1[(k4 + 2) * 256 + j];
    float w3 = Wr1[(k4 + 3) * 256 + j];
#pragma unroll
    for (int p = 0; p < PPB; ++p) {
      float4 f = *(const float4*)&feat[p][k4];
      acc[p] = fmaf(f.x, w0, acc[p]);
      acc[p] = fmaf(f.y, w1, acc[p]);
      acc[p] = fmaf(f.z, wv2, acc[p]);
      acc[p] = fmaf(f.w, w3, acc[p]);
    }
  }
  int wv = tid >> 6;
#pragma unroll
  for (int p = 0; p < PPB; ++p) {
    float hid = fmaxf(acc[p] + b1v, 0.f);
    float v = hid * w2;
    for (int o = 32; o > 0; o >>= 1) v += __shfl_down(v, o, 64);
    if ((tid & 63) == 0) red[wv][p] = v;
  }
  __syncthreads();
  if (tid < PPB) {
    int p = base + tid;
    if (p < P) out[p] = red[0][tid] + red[1][tid] + red[2][tid] + red[3][tid] + br2[0];
  }
}

extern "C" void kernel_launch(void* const* d_in, const int* in_sizes, int n_in,
                              void* d_out, int out_size, void* d_ws, size_t ws_size,
                              hipStream_t stream) {
  const float* x = (const float*)d_in[0];
  const int* ei = (const int*)d_in[1];
  const int* batch = (const int*)d_in[2];
  const int* dp = (const int*)d_in[3];
  const float* W1 = (const float*)d_in[4];
  const float* b1 = (const float*)d_in[5];
  const float* W2 = (const float*)d_in[6];
  const float* b2 = (const float*)d_in[7];
  const float* Wr1 = (const float*)d_in[8];
  const float* br1 = (const float*)d_in[9];
  const float* Wr2 = (const float*)d_in[10];
  const float* br2 = (const float*)d_in[11];
  float* out = (float*)d_out;

  int N = in_sizes[0] / 64;
  int E = in_sizes[1] / 2;
  int P = in_sizes[3] / 2;
  int G = N_GRAPHS;
  const int* src = ei;
  const int* dstp = ei + E;

  char* ws = (char*)d_ws;
  size_t o = 0;
  auto alloc = [&](size_t bytes) {
    void* p = ws + o;
    o += (bytes + 255) & ~(size_t)255;
    return p;
  };
  float* isq = (float*)alloc((size_t)N * 4);
  int* cnt = (int*)alloc((size_t)N * 4);
  int* fill = (int*)alloc((size_t)N * 4);
  int* rs = (int*)alloc((size_t)(N + 1) * 4);
  int* bsum = (int*)alloc(1024 * 4);
  int* goff = (int*)alloc((size_t)(G + 1) * 4);
  int* csr = (int*)alloc((size_t)E * 4);
  float* hbuf = (float*)alloc((size_t)N * 64 * 4);
  float* abuf = (float*)alloc((size_t)N * 64 * 4);
  float* ge = (float*)alloc((size_t)G * 64 * 4);

  hipMemsetAsync(cnt, 0, (size_t)N * 4, stream);
  hipMemsetAsync(fill, 0, (size_t)N * 4, stream);
  count_in_deg<<<2048, 256, 0, stream>>>(dstp, cnt, E);
  inv_sqrt_deg<<<(N + 255) / 256, 256, 0, stream>>>(cnt, isq, N);

  // CSR build
  int nb = (N + SCAN_CHUNK - 1) / SCAN_CHUNK;  // 245 for 500k
  scan1<<<nb, 256, 0, stream>>>(cnt, rs, bsum, N);
  scan2<<<1, 256, 0, stream>>>(bsum, nb);
  scan3<<<(N + 1 + 255) / 256, 256, 0, stream>>>(rs, bsum, N + 1);
  csr_fill<<<2048, 256, 0, stream>>>(src, dstp, rs, fill, csr, E);

  int tiles = (N + 63) / 64;
  // conv1
  gemm_n64<<<tiles, 256, 0, stream>>>(x, W1, hbuf, N);
  gather_conv<<<4096, 256, 0, stream>>>(hbuf, csr, rs, isq, b1, abuf, N);
  // conv2
  gemm_n64<<<tiles, 256, 0, stream>>>(abuf, W2, hbuf, N);
  gather_conv<<<4096, 256, 0, stream>>>(hbuf, csr, rs, isq, b2, abuf, N);
  // pool
  seg_offsets<<<(N + 255) / 256, 256, 0, stream>>>(batch, goff, N, G);
  pool_mean<<<2048, 256, 0, stream>>>(abuf, goff, ge, G);
  // pair MLP
  pair_mlp<<<(P + PPB - 1) / PPB, 256, 0, stream>>>(ge, dp, Wr1, br1, Wr2, br2, out, P);
}

// Round 3
// 858.587 us; speedup vs baseline: 1.5932x; 1.1178x over previous
//
#include <hip/hip_runtime.h>
#include <cstdint>

#define N_GRAPHS 20000
#define SCAN_CHUNK 2048
#define GK 4  // dst streams per wave in gather

// ---------------- degree ----------------
__global__ void count_in_deg(const int* __restrict__ dst, int* __restrict__ cnt, int E) {
  int i = blockIdx.x * blockDim.x + threadIdx.x;
  int stride = gridDim.x * blockDim.x;
  for (int e = i; e < E; e += stride) atomicAdd(&cnt[dst[e]], 1);
}

__global__ void inv_sqrt_deg(const int* __restrict__ cnt, float* __restrict__ isq, int N) {
  int i = blockIdx.x * blockDim.x + threadIdx.x;
  if (i < N) isq[i] = rsqrtf((float)(cnt[i] + 1));
}

// ---------------- prefix scan (exclusive) of cnt[N] -> rs[N+1] ----------------
__global__ __launch_bounds__(256) void scan1(const int* __restrict__ cnt, int* __restrict__ rs,
                                             int* __restrict__ bsum, int N) {
  __shared__ int lds[256];
  int t = threadIdx.x;
  int base = blockIdx.x * SCAN_CHUNK + t * 8;
  int v[8];
  int s = 0;
#pragma unroll
  for (int i = 0; i < 8; ++i) {
    v[i] = (base + i < N) ? cnt[base + i] : 0;
    s += v[i];
  }
  lds[t] = s;
  __syncthreads();
  for (int off = 1; off < 256; off <<= 1) {
    int x = (t >= off) ? lds[t - off] : 0;
    __syncthreads();
    lds[t] += x;
    __syncthreads();
  }
  if (t == 255) bsum[blockIdx.x] = lds[255];
  int run = (t > 0) ? lds[t - 1] : 0;
#pragma unroll
  for (int i = 0; i < 8; ++i) {
    if (base + i <= N) rs[base + i] = run;
    run += v[i];
  }
}

__global__ __launch_bounds__(256) void scan2(int* __restrict__ bsum, int nb) {
  __shared__ int lds[256];
  int t = threadIdx.x;
  lds[t] = (t < nb) ? bsum[t] : 0;
  __syncthreads();
  for (int off = 1; off < 256; off <<= 1) {
    int x = (t >= off) ? lds[t - off] : 0;
    __syncthreads();
    lds[t] += x;
    __syncthreads();
  }
  if (t < nb) bsum[t] = (t > 0) ? lds[t - 1] : 0;  // exclusive
}

__global__ void scan3(int* __restrict__ rs, const int* __restrict__ bsum, int Np1) {
  int i = blockIdx.x * blockDim.x + threadIdx.x;
  if (i < Np1) rs[i] += bsum[i / SCAN_CHUNK];
}

// ---------------- CSR fill (consumes cnt -> zeros) ----------------
__global__ void csr_fill(const int* __restrict__ src, const int* __restrict__ dst,
                         const int* __restrict__ rs, int* __restrict__ cnt,
                         int* __restrict__ csr, int E) {
  int i = blockIdx.x * blockDim.x + threadIdx.x;
  int stride = gridDim.x * blockDim.x;
  for (int e = i; e < E; e += stride) {
    int d = dst[e];
    int pos = rs[d] + atomicSub(&cnt[d], 1) - 1;
    csr[pos] = src[e];
  }
}

// ---------------- node GEMM + row scale: out[r,:] = (in[r,:] @ W) * isq[r] ----------------
__global__ __launch_bounds__(256) void gemm_n64(const float* __restrict__ in,
                                                const float* __restrict__ W,
                                                const float* __restrict__ isq,
                                                float* __restrict__ out, int N) {
  __shared__ float Wl[64 * 64];
  __shared__ float Rl[64 * 65];
  int tid = threadIdx.x;
#pragma unroll
  for (int v = 0; v < 4; ++v) {
    int u = tid + v * 256;
    *(float4*)&Wl[u * 4] = *(const float4*)&W[u * 4];
  }
  long base_row = (long)blockIdx.x * 64;
#pragma unroll
  for (int v = 0; v < 4; ++v) {
    int u = tid + v * 256;
    int r = u >> 4;
    int k = (u & 15) * 4;
    long row = base_row + r;
    float4 val = make_float4(0.f, 0.f, 0.f, 0.f);
    if (row < N) val = *(const float4*)&in[row * 64 + k];
    *(float4*)&Rl[r * 65 + k] = val;
  }
  __syncthreads();
  int r = tid >> 2;
  int c0 = (tid & 3) * 16;
  float acc[16];
#pragma unroll
  for (int j = 0; j < 16; ++j) acc[j] = 0.f;
#pragma unroll 4
  for (int k = 0; k < 64; ++k) {
    float a = Rl[r * 65 + k];
#pragma unroll
    for (int j = 0; j < 16; ++j) acc[j] += a * Wl[k * 64 + c0 + j];
  }
  long row = base_row + r;
  if (row < N) {
    float sc = isq[row];
#pragma unroll
    for (int v = 0; v < 4; ++v) {
      *(float4*)&out[row * 64 + c0 + v * 4] =
          make_float4(acc[v * 4] * sc, acc[v * 4 + 1] * sc, acc[v * 4 + 2] * sc,
                      acc[v * 4 + 3] * sc);
    }
  }
}

// ------- gather conv: out[d] = relu(isq[d]*(sum_{s in N(d)} hp[s] + hp[d]) + b) -------
// hp = (in@W)*isq. 4 dst streams per wave for memory-level parallelism.
__global__ __launch_bounds__(256) void gather_conv(const float* __restrict__ hp,
                                                   const int* __restrict__ csr,
                                                   const int* __restrict__ rs,
                                                   const float* __restrict__ isq,
                                                   const float* __restrict__ bias,
                                                   float* __restrict__ out, int N) {
  int lane = threadIdx.x & 63;
  int wid = (blockIdx.x * blockDim.x + threadIdx.x) >> 6;
  int nw = (gridDim.x * blockDim.x) >> 6;
  float bv = bias[lane];
  for (int d0 = wid * GK; d0 < N; d0 += nw * GK) {
    int jj[GK], je[GK];
    float ac[GK];
#pragma unroll
    for (int k = 0; k < GK; ++k) {
      int d = d0 + k;
      bool v = d < N;
      jj[k] = v ? rs[d] : 0;
      je[k] = v ? rs[d + 1] : 0;
      ac[k] = v ? hp[(long)d * 64 + lane] : 0.f;  // self-loop term
    }
    while (true) {
      bool any = false;
      int sidx[GK];
      bool act[GK];
#pragma unroll
      for (int k = 0; k < GK; ++k) {
        act[k] = jj[k] < je[k];
        if (act[k]) {
          sidx[k] = csr[jj[k]];
          any = true;
        }
      }
      if (!any) break;
#pragma unroll
      for (int k = 0; k < GK; ++k)
        if (act[k]) ac[k] += hp[(long)sidx[k] * 64 + lane];
#pragma unroll
      for (int k = 0; k < GK; ++k) jj[k] += act[k] ? 1 : 0;
    }
#pragma unroll
    for (int k = 0; k < GK; ++k) {
      int d = d0 + k;
      if (d < N) {
        out[(long)d * 64 + lane] = fmaxf(fmaf(ac[k], isq[d], bv), 0.f);
      }
    }
  }
}

// ---------------- graph segment offsets from sorted batch_idx ----------------
__global__ void seg_offsets(const int* __restrict__ batch, int* __restrict__ off, int N, int G) {
  int i = blockIdx.x * blockDim.x + threadIdx.x;
  if (i >= N) return;
  int b = batch[i];
  if (i == 0) {
    for (int g = 0; g <= b; ++g) off[g] = 0;
  } else {
    int pb = batch[i - 1];
    for (int g = pb + 1; g <= b; ++g) off[g] = i;
  }
  if (i == N - 1) {
    for (int g = b + 1; g <= G; ++g) off[g] = N;
  }
}

// ---------------- mean pool: wave per graph ----------------
__global__ void pool_mean(const float* __restrict__ e2, const int* __restrict__ off,
                          float* __restrict__ ge, int G) {
  int lane = threadIdx.x & 63;
  int wid = (blockIdx.x * blockDim.x + threadIdx.x) >> 6;
  int nw = (gridDim.x * blockDim.x) >> 6;
  for (int g = wid; g < G; g += nw) {
    int s = off[g];
    int e = off[g + 1];
    float sum = 0.f;
    for (int n = s; n < e; ++n) sum += e2[(long)n * 64 + lane];
    ge[(long)g * 64 + lane] = sum / fmaxf((float)(e - s), 1.f);
  }
}

// ---------------- pair MLP ----------------
#define PPB 16
__global__ __launch_bounds__(256) void pair_mlp(const float* __restrict__ ge,
                                                const int* __restrict__ dp,
                                                const float* __restrict__ Wr1,
                                                const float* __restrict__ br1,
                                                const float* __restrict__ Wr2,
                                                const float* __restrict__ br2,
                                                float* __restrict__ out, int P) {
  __shared__ float feat[PPB][128];
  __shared__ int pidx[2][PPB];
  __shared__ float red[4][PPB];
  int tid = threadIdx.x;
  int base = blockIdx.x * PPB;
  if (tid < PPB) {
    int p = base + tid;
    pidx[0][tid] = (p < P) ? dp[p] : 0;
    pidx[1][tid] = (p < P) ? dp[P + p] : 0;
  }
  __syncthreads();
#pragma unroll
  for (int i = 0; i < 8; ++i) {
    int f = tid + i * 256;
    int p = f >> 7;
    int k = f & 127;
    int g = (k < 64) ? pidx[0][p] : pidx[1][p];
    feat[p][k] = ge[(long)g * 64 + (k & 63)];
  }
  __syncthreads();
  int j = tid;
  float w2 = Wr2[j];
  float b1v = br1[j];
  float acc[PPB];
#pragma unroll
  for (int p = 0; p < PPB; ++p) acc[p] = 0.f;
  for (int k4 = 0; k4 < 128; k4 += 4) {
    float w0 = Wr1[(k4 + 0) * 256 + j];
    float w1 = Wr1[(k4 + 1) * 256 + j];
    float wv2 = Wr1[(k4 + 2) * 256 + j];
    float w3 = Wr1[(k4 + 3) * 256 + j];
#pragma unroll
    for (int p = 0; p < PPB; ++p) {
      float4 f = *(const float4*)&feat[p][k4];
      acc[p] = fmaf(f.x, w0, acc[p]);
      acc[p] = fmaf(f.y, w1, acc[p]);
      acc[p] = fmaf(f.z, wv2, acc[p]);
      acc[p] = fmaf(f.w, w3, acc[p]);
    }
  }
  int wv = tid >> 6;
#pragma unroll
  for (int p = 0; p < PPB; ++p) {
    float hid = fmaxf(acc[p] + b1v, 0.f);
    float v = hid * w2;
    for (int o = 32; o > 0; o >>= 1) v += __shfl_down(v, o, 64);
    if ((tid & 63) == 0) red[wv][p] = v;
  }
  __syncthreads();
  if (tid < PPB) {
    int p = base + tid;
    if (p < P) out[p] = red[0][tid] + red[1][tid] + red[2][tid] + red[3][tid] + br2[0];
  }
}

extern "C" void kernel_launch(void* const* d_in, const int* in_sizes, int n_in,
                              void* d_out, int out_size, void* d_ws, size_t ws_size,
                              hipStream_t stream) {
  const float* x = (const float*)d_in[0];
  const int* ei = (const int*)d_in[1];
  const int* batch = (const int*)d_in[2];
  const int* dp = (const int*)d_in[3];
  const float* W1 = (const float*)d_in[4];
  const float* b1 = (const float*)d_in[5];
  const float* W2 = (const float*)d_in[6];
  const float* b2 = (const float*)d_in[7];
  const float* Wr1 = (const float*)d_in[8];
  const float* br1 = (const float*)d_in[9];
  const float* Wr2 = (const float*)d_in[10];
  const float* br2 = (const float*)d_in[11];
  float* out = (float*)d_out;

  int N = in_sizes[0] / 64;
  int E = in_sizes[1] / 2;
  int P = in_sizes[3] / 2;
  int G = N_GRAPHS;
  const int* src = ei;
  const int* dstp = ei + E;

  char* ws = (char*)d_ws;
  size_t o = 0;
  auto alloc = [&](size_t bytes) {
    void* p = ws + o;
    o += (bytes + 255) & ~(size_t)255;
    return p;
  };
  float* isq = (float*)alloc((size_t)N * 4);
  int* cnt = (int*)alloc((size_t)N * 4);
  int* rs = (int*)alloc((size_t)(N + 1) * 4);
  int* bsum = (int*)alloc(1024 * 4);
  int* goff = (int*)alloc((size_t)(G + 1) * 4);
  int* csr = (int*)alloc((size_t)E * 4);
  float* hbuf = (float*)alloc((size_t)N * 64 * 4);
  float* abuf = (float*)alloc((size_t)N * 64 * 4);
  float* ge = (float*)alloc((size_t)G * 64 * 4);

  hipMemsetAsync(cnt, 0, (size_t)N * 4, stream);
  count_in_deg<<<2048, 256, 0, stream>>>(dstp, cnt, E);
  inv_sqrt_deg<<<(N + 255) / 256, 256, 0, stream>>>(cnt, isq, N);

  // CSR build
  int nb = (N + SCAN_CHUNK - 1) / SCAN_CHUNK;
  scan1<<<nb, 256, 0, stream>>>(cnt, rs, bsum, N);
  scan2<<<1, 256, 0, stream>>>(bsum, nb);
  scan3<<<(N + 1 + 255) / 256, 256, 0, stream>>>(rs, bsum, N + 1);
  csr_fill<<<2048, 256, 0, stream>>>(src, dstp, rs, cnt, csr, E);  // cnt -> zeros

  int tiles = (N + 63) / 64;
  int gblocks = (N + GK * 4 - 1) / (GK * 4);  // 4 waves/block, GK dsts/wave
  // conv1
  gemm_n64<<<tiles, 256, 0, stream>>>(x, W1, isq, hbuf, N);
  gather_conv<<<gblocks, 256, 0, stream>>>(hbuf, csr, rs, isq, b1, abuf, N);
  // conv2
  gemm_n64<<<tiles, 256, 0, stream>>>(abuf, W2, isq, hbuf, N);
  gather_conv<<<gblocks, 256, 0, stream>>>(hbuf, csr, rs, isq, b2, abuf, N);
  // pool
  seg_offsets<<<(N + 255) / 256, 256, 0, stream>>>(batch, goff, N, G);
  pool_mean<<<2048, 256, 0, stream>>>(abuf, goff, ge, G);
  // pair MLP
  pair_mlp<<<(P + PPB - 1) / PPB, 256, 0, stream>>>(ge, dp, Wr1, br1, Wr2, br2, out, P);
}